// Round 4
// baseline (380.715 us; speedup 1.0000x reference)
//
#include <hip/hip_runtime.h>
#include <stdint.h>

// Self-attention, B=8 S=2048 D=E=512, fp32 in/out, bf16 MFMA internally.
//   xconv:    x fp32 -> bf16
//   wconv:    W[k][n] fp32 -> Wt[n][k] bf16 (x3)
//   qkv_gemm: m97-style async-staged GEMM; Q,K row-major bf16; V transposed [B,E,S] bf16
//   attn:     flash (no-max softmax), 32 Q-rows/block, 64-key LDS tiles, wave = 16
//             exclusive keys x 32 rows (1x K amplification), V direct from L2,
//             alias-safe single-buffer K pipeline (2 barriers/iter), 2 blocks/CU.

using f32x4 = __attribute__((ext_vector_type(4))) float;
using s16x8 = __attribute__((ext_vector_type(8))) short;
using u16x4 = __attribute__((ext_vector_type(4))) unsigned short;

#define S_LEN 2048
#define EMB   512

#define ASYNC16(g, l)                                                     \
  __builtin_amdgcn_global_load_lds(                                       \
      (const __attribute__((address_space(1))) void*)(g),                 \
      (__attribute__((address_space(3))) void*)(l), 16, 0, 0)

__device__ __forceinline__ unsigned short f2bf(float f) {
  union { float f; unsigned u; } v; v.f = f;
  unsigned r = v.u + 0x7fffu + ((v.u >> 16) & 1u);   // RNE
  return (unsigned short)(r >> 16);
}

// ---------------- kernel 0: x fp32 -> bf16 ----------------
__global__ __launch_bounds__(256) void xconv_kernel(
    const float* __restrict__ x, short* __restrict__ xb) {
  int i = (blockIdx.x * 256 + threadIdx.x) * 8;
  f32x4 a = *(const f32x4*)(x + i);
  f32x4 b = *(const f32x4*)(x + i + 4);
  s16x8 h;
  h[0] = (short)f2bf(a[0]); h[1] = (short)f2bf(a[1]);
  h[2] = (short)f2bf(a[2]); h[3] = (short)f2bf(a[3]);
  h[4] = (short)f2bf(b[0]); h[5] = (short)f2bf(b[1]);
  h[6] = (short)f2bf(b[2]); h[7] = (short)f2bf(b[3]);
  *(s16x8*)(xb + i) = h;
}

// ---------------- kernel 1: weight transpose + convert ----------------
__global__ __launch_bounds__(256) void wconv_kernel(
    const float* __restrict__ Wq, const float* __restrict__ Wk,
    const float* __restrict__ Wv, short* __restrict__ Wt) {
  int idx = blockIdx.x * 256 + threadIdx.x;
  int mat = idx >> 18;
  int r   = idx & 262143;
  int n   = r >> 9;
  int k   = r & 511;
  const float* W = (mat == 0) ? Wq : (mat == 1) ? Wk : Wv;
  Wt[idx] = (short)f2bf(W[k * 512 + n]);
}

// ---------------- kernel 2: QKV projection GEMM (m97 structure) ----------------
__global__ __launch_bounds__(256) void qkv_gemm(
    const short* __restrict__ xb, const short* __restrict__ Wt,
    const float* __restrict__ bq, const float* __restrict__ bk,
    const float* __restrict__ bv,
    short* __restrict__ Qg, short* __restrict__ Kg, short* __restrict__ VTg) {
  __shared__ __align__(16) short As[128 * 64];   // 16B chunk c stored at c^(row&7)
  __shared__ __align__(16) short Bs[128 * 64];
  int gid = blockIdx.x;
  int mat = gid >> 9;
  int rem = gid & 511;
  int mt  = rem & 127, nt = rem >> 7;
  int m0  = mt << 7,   n0 = nt << 7;
  const short* W    = Wt + (size_t)mat * 262144;
  const float* bias = (mat == 0) ? bq : (mat == 1) ? bk : bv;

  int tid = threadIdx.x, lane = tid & 63, wv = tid >> 6;
  int l16 = lane & 15, quad = lane >> 4;
  int wr = (wv & 1) << 6, wc = (wv >> 1) << 6;
  int drow = lane >> 3;
  int dchk = (lane & 7) ^ drow;

  const f32x4 Z4 = {0.f, 0.f, 0.f, 0.f};
  f32x4 acc[4][4];
#pragma unroll
  for (int a = 0; a < 4; ++a)
#pragma unroll
    for (int c = 0; c < 4; ++c) acc[a][c] = Z4;

  for (int it = 0; it < 8; ++it) {
    int k0 = it << 6;
    __syncthreads();
#pragma unroll
    for (int i = 0; i < 4; ++i) {
      int g   = wv * 4 + i;
      int row = g * 8 + drow;
      ASYNC16(xb + (size_t)(m0 + row) * 512 + k0 + dchk * 8, &As[g * 512]);
    }
#pragma unroll
    for (int i = 0; i < 4; ++i) {
      int g   = wv * 4 + i;
      int row = g * 8 + drow;
      ASYNC16(W + (size_t)(n0 + row) * 512 + k0 + dchk * 8, &Bs[g * 512]);
    }
    __syncthreads();
#pragma unroll
    for (int kk = 0; kk < 2; ++kk) {
      s16x8 af[4], bfr[4];
#pragma unroll
      for (int rb = 0; rb < 4; ++rb) {
        int row = wr + rb * 16 + l16;
        int c   = kk * 4 + quad;
        af[rb] = *(const s16x8*)(As + row * 64 + ((c ^ (row & 7)) * 8));
      }
#pragma unroll
      for (int cb = 0; cb < 4; ++cb) {
        int row = wc + cb * 16 + l16;
        int c   = kk * 4 + quad;
        bfr[cb] = *(const s16x8*)(Bs + row * 64 + ((c ^ (row & 7)) * 8));
      }
#pragma unroll
      for (int rb = 0; rb < 4; ++rb)
#pragma unroll
        for (int cb = 0; cb < 4; ++cb)
          acc[rb][cb] = __builtin_amdgcn_mfma_f32_16x16x32_bf16(af[rb], bfr[cb], acc[rb][cb], 0, 0, 0);
    }
  }

  float bsv[4];
#pragma unroll
  for (int cb = 0; cb < 4; ++cb) bsv[cb] = bias[n0 + wc + cb * 16 + l16];

  if (mat < 2) {
    short* D = (mat == 0) ? Qg : Kg;
#pragma unroll
    for (int rb = 0; rb < 4; ++rb)
#pragma unroll
      for (int cb = 0; cb < 4; ++cb)
#pragma unroll
        for (int r = 0; r < 4; ++r) {
          int m = m0 + wr + rb * 16 + quad * 4 + r;
          D[(size_t)m * 512 + n0 + wc + cb * 16 + l16] =
              (short)f2bf(acc[rb][cb][r] + bsv[cb]);
        }
  } else {
#pragma unroll
    for (int rb = 0; rb < 4; ++rb)
#pragma unroll
      for (int cb = 0; cb < 4; ++cb) {
        u16x4 h;
#pragma unroll
        for (int r = 0; r < 4; ++r) h[r] = f2bf(acc[rb][cb][r] + bsv[cb]);
        int m  = m0 + wr + rb * 16 + quad * 4;
        int bb = m >> 11, s = m & 2047;
        int e  = n0 + wc + cb * 16 + l16;
        *(u16x4*)(VTg + ((size_t)bb * 512 + e) * 2048 + s) = h;
      }
  }
}

// ---------------- kernel 3: flash attention v4 ----------------
// grid = 512 (b = blk&7 -> XCD L2 pinning), 32 Q-rows/block, 4 waves.
// K tile: 64 keys x 512 E in LDS [key][chunk^(key&7)] (64 KB, single buffer).
// wave w: keys [w*16, w*16+16) exclusively, all 32 rows (K-frag shared by both
// row groups -> 1x LDS amplification). V read directly from global (L2).
// ~69 KB LDS -> 2 blocks/CU; VGPR capped 256 via launch_bounds.
__global__ __launch_bounds__(256, 2) void attn_kernel(
    const short* __restrict__ Qg, const short* __restrict__ Kg,
    const short* __restrict__ VTg, float* __restrict__ out) {
  __shared__ __align__(16) short Kt[64 * 512];   // 64 KB
  __shared__ __align__(16) short Pl[32 * 72];    // 4.5 KB, row stride 72 shorts
  __shared__ float Ls[4][32];
  const float SCL2 = 0.06375871855f;  // log2(e)/sqrt(512)

  int b = blockIdx.x & 7, qt = blockIdx.x >> 3;
  int s0 = qt << 5;
  int tid = threadIdx.x, lane = tid & 63, wv = tid >> 6;
  int l16 = lane & 15, quad = lane >> 4;
  int kq = wv;                        // key-quarter
  int e0 = wv << 7;                   // E-chunk for PV

  const short* Kb = Kg  + ((size_t)b * S_LEN) * 512;
  const short* Vb = VTg + ((size_t)b * 512) * 2048;

  // ---- prologue: stage K tile 0 (64 rows, 16 per wave), load Q frags ----
#pragma unroll
  for (int i = 0; i < 16; ++i) {
    int r = wv * 16 + i;              // r&7 == i&7 (wv*16 % 8 == 0)
    ASYNC16(Kb + (size_t)r * 512 + ((lane ^ (i & 7)) * 8), &Kt[r * 512]);
  }

  // Q: all 32 rows per wave; qf[a][kk] covers rows a*16+l16, k-chunk kk
  s16x8 qf[2][16];
#pragma unroll
  for (int a = 0; a < 2; ++a) {
    const short* qrow = Qg + ((size_t)b * S_LEN + s0 + a * 16 + l16) * 512 + quad * 8;
#pragma unroll
    for (int kk = 0; kk < 16; ++kk) qf[a][kk] = *(const s16x8*)(qrow + kk * 32);
  }

  const f32x4 Z4 = {0.f, 0.f, 0.f, 0.f};
  f32x4 acc[2][8];
#pragma unroll
  for (int a = 0; a < 2; ++a)
#pragma unroll
    for (int cb = 0; cb < 8; ++cb) acc[a][cb] = Z4;
  f32x4 lsum[2] = {Z4, Z4};

  // V fragment base: lane part of address (e = e0 + cb*16 + l16)
  const short* vrow = Vb + (size_t)(e0 + l16) * 2048 + quad * 8;

  __syncthreads();                    // K tile 0 ready

  for (int kt = 0; kt < 32; ++kt) {
    // ---- QK: S[32 rows x 16 keys(kq)], K-frag shared across row groups ----
    int krow = kq * 16 + l16;
    const short* kb = &Kt[krow * 512];
    int ksw = krow & 7;
    f32x4 s_a = Z4, s_b = Z4;
#pragma unroll
    for (int kk = 0; kk < 16; ++kk) {
      s16x8 kf = *(const s16x8*)(kb + ((kk * 4 + quad) ^ ksw) * 8);
      s_a = __builtin_amdgcn_mfma_f32_16x16x32_bf16(qf[0][kk], kf, s_a, 0, 0, 0);
      s_b = __builtin_amdgcn_mfma_f32_16x16x32_bf16(qf[1][kk], kf, s_b, 0, 0, 0);
    }

    // ---- no-max softmax; P write; per-lane row-sum accumulate ----
#pragma unroll
    for (int r = 0; r < 4; ++r) {
      float p0 = exp2f(s_a[r] * SCL2);
      float p1 = exp2f(s_b[r] * SCL2);
      lsum[0][r] += p0;
      lsum[1][r] += p1;
      Pl[(quad * 4 + r) * 72 + kq * 16 + l16]        = (short)f2bf(p0);
      Pl[(16 + quad * 4 + r) * 72 + kq * 16 + l16]   = (short)f2bf(p1);
    }

    __syncthreads();   // (1) Kt reads done; P visible

    // ---- issue K-DMA(kt+1): writes Kt; PV reads only Pl + global V ----
    if (kt + 1 < 32) {
      size_t adv = (size_t)(kt + 1) * 64 * 512;
#pragma unroll
      for (int i = 0; i < 16; ++i) {
        int r = wv * 16 + i;
        ASYNC16(Kb + adv + (size_t)r * 512 + ((lane ^ (i & 7)) * 8), &Kt[r * 512]);
      }
    }

    // ---- PV: O[32 x 128chunk(e0)] += P[32x64] @ V[64 x 128chunk] ----
    const short* vt = vrow + kt * 64;
#pragma unroll
    for (int kc = 0; kc < 2; ++kc) {
      s16x8 pf0 = *(const s16x8*)(Pl + l16 * 72 + kc * 32 + quad * 8);
      s16x8 pf1 = *(const s16x8*)(Pl + (16 + l16) * 72 + kc * 32 + quad * 8);
      s16x8 vf[8];
#pragma unroll
      for (int cb = 0; cb < 8; ++cb)
        vf[cb] = *(const s16x8*)(vt + (size_t)cb * 32768 + kc * 32);
#pragma unroll
      for (int cb = 0; cb < 8; ++cb) {
        acc[0][cb] = __builtin_amdgcn_mfma_f32_16x16x32_bf16(pf0, vf[cb], acc[0][cb], 0, 0, 0);
        acc[1][cb] = __builtin_amdgcn_mfma_f32_16x16x32_bf16(pf1, vf[cb], acc[1][cb], 0, 0, 0);
      }
    }

    __syncthreads();   // (2) PV done (Pl free); K-DMA(kt+1) drained
  }

  // ---- epilogue: reduce row sums (16 keys -> wave, then across 4 waves) ----
#pragma unroll
  for (int a = 0; a < 2; ++a)
#pragma unroll
    for (int r = 0; r < 4; ++r) {
      float v = lsum[a][r];
      v += __shfl_xor(v, 1);
      v += __shfl_xor(v, 2);
      v += __shfl_xor(v, 4);
      v += __shfl_xor(v, 8);
      lsum[a][r] = v;
    }
  if (l16 == 0) {
#pragma unroll
    for (int a = 0; a < 2; ++a)
#pragma unroll
      for (int r = 0; r < 4; ++r) Ls[wv][a * 16 + quad * 4 + r] = lsum[a][r];
  }
  __syncthreads();

  float linv[2][4];
#pragma unroll
  for (int a = 0; a < 2; ++a)
#pragma unroll
    for (int r = 0; r < 4; ++r) {
      int srow = a * 16 + quad * 4 + r;
      linv[a][r] = 1.0f / (Ls[0][srow] + Ls[1][srow] + Ls[2][srow] + Ls[3][srow]);
    }
#pragma unroll
  for (int a = 0; a < 2; ++a)
#pragma unroll
    for (int cb = 0; cb < 8; ++cb)
#pragma unroll
      for (int r = 0; r < 4; ++r)
        out[((size_t)b * S_LEN + s0 + a * 16 + quad * 4 + r) * 512 + e0 + cb * 16 + l16] =
            acc[a][cb][r] * linv[a][r];
}

// ---------------- host launch ----------------
extern "C" void kernel_launch(void* const* d_in, const int* in_sizes, int n_in,
                              void* d_out, int out_size, void* d_ws, size_t ws_size,
                              hipStream_t stream) {
  const float* x  = (const float*)d_in[0];
  const float* Wq = (const float*)d_in[1];
  const float* bq = (const float*)d_in[2];
  const float* Wk = (const float*)d_in[3];
  const float* bk = (const float*)d_in[4];
  const float* Wv = (const float*)d_in[5];
  const float* bv = (const float*)d_in[6];

  short* Wt  = (short*)d_ws;
  short* xb  = (short*)((char*)d_ws + 1572864);
  short* Qg  = xb + (size_t)8388608;
  short* Kg  = Qg + (size_t)8388608;
  short* VTg = Kg + (size_t)8388608;

  xconv_kernel<<<4096, 256, 0, stream>>>(x, xb);
  wconv_kernel<<<3072, 256, 0, stream>>>(Wq, Wk, Wv, Wt);
  qkv_gemm<<<1536, 256, 0, stream>>>(xb, Wt, bq, bk, bv, Qg, Kg, VTg);
  attn_kernel<<<512, 256, 0, stream>>>(Qg, Kg, VTg, (float*)d_out);
}

// Round 5
// 290.080 us; speedup vs baseline: 1.3124x; 1.3124x over previous
//
#include <hip/hip_runtime.h>
#include <stdint.h>

// Self-attention, B=8 S=2048 D=E=512, fp32 in/out, bf16 MFMA internally.
//   conv:     x fp32 -> bf16 AND W[k][n] fp32 -> Wt[n][k] bf16 (merged launch)
//   qkv_gemm: m97-style async-staged GEMM; Q,K row-major bf16; V transposed [B,E,S] bf16
//   attn:     R3 skeleton (32 Q-rows/block, 32-key LDS K-tiles, 2 blocks/CU,
//             alias-safe single-buffer K pipeline) + V fragments in REGISTERS,
//             loaded at iter top so they are older than the K-DMA in vmcnt order.

using f32x4 = __attribute__((ext_vector_type(4))) float;
using s16x8 = __attribute__((ext_vector_type(8))) short;
using u16x4 = __attribute__((ext_vector_type(4))) unsigned short;

#define S_LEN 2048
#define EMB   512

#define ASYNC16(g, l)                                                     \
  __builtin_amdgcn_global_load_lds(                                       \
      (const __attribute__((address_space(1))) void*)(g),                 \
      (__attribute__((address_space(3))) void*)(l), 16, 0, 0)

__device__ __forceinline__ unsigned short f2bf(float f) {
  union { float f; unsigned u; } v; v.f = f;
  unsigned r = v.u + 0x7fffu + ((v.u >> 16) & 1u);   // RNE
  return (unsigned short)(r >> 16);
}

// ---------------- kernel 0+1 merged: x conv & weight transpose ----------------
__global__ __launch_bounds__(256) void conv_kernel(
    const float* __restrict__ x, const float* __restrict__ Wq,
    const float* __restrict__ Wk, const float* __restrict__ Wv,
    short* __restrict__ xb, short* __restrict__ Wt) {
  int bid = blockIdx.x;
  if (bid < 4096) {                       // x: 8M elements, 8 per thread
    int i = (bid * 256 + threadIdx.x) * 8;
    f32x4 a = *(const f32x4*)(x + i);
    f32x4 b = *(const f32x4*)(x + i + 4);
    s16x8 h;
    h[0] = (short)f2bf(a[0]); h[1] = (short)f2bf(a[1]);
    h[2] = (short)f2bf(a[2]); h[3] = (short)f2bf(a[3]);
    h[4] = (short)f2bf(b[0]); h[5] = (short)f2bf(b[1]);
    h[6] = (short)f2bf(b[2]); h[7] = (short)f2bf(b[3]);
    *(s16x8*)(xb + i) = h;
  } else {                                // W transpose: 3*512*512
    int idx = (bid - 4096) * 256 + threadIdx.x;
    int mat = idx >> 18;
    int r   = idx & 262143;
    int n   = r >> 9;
    int k   = r & 511;
    const float* W = (mat == 0) ? Wq : (mat == 1) ? Wk : Wv;
    Wt[idx] = (short)f2bf(W[k * 512 + n]);
  }
}

// ---------------- kernel 2: QKV projection GEMM (m97 structure) ----------------
__global__ __launch_bounds__(256) void qkv_gemm(
    const short* __restrict__ xb, const short* __restrict__ Wt,
    const float* __restrict__ bq, const float* __restrict__ bk,
    const float* __restrict__ bv,
    short* __restrict__ Qg, short* __restrict__ Kg, short* __restrict__ VTg) {
  __shared__ __align__(16) short As[128 * 64];   // 16B chunk c stored at c^(row&7)
  __shared__ __align__(16) short Bs[128 * 64];
  int gid = blockIdx.x;
  int mat = gid >> 9;
  int rem = gid & 511;
  int mt  = rem & 127, nt = rem >> 7;
  int m0  = mt << 7,   n0 = nt << 7;
  const short* W    = Wt + (size_t)mat * 262144;
  const float* bias = (mat == 0) ? bq : (mat == 1) ? bk : bv;

  int tid = threadIdx.x, lane = tid & 63, wv = tid >> 6;
  int l16 = lane & 15, quad = lane >> 4;
  int wr = (wv & 1) << 6, wc = (wv >> 1) << 6;
  int drow = lane >> 3;
  int dchk = (lane & 7) ^ drow;

  const f32x4 Z4 = {0.f, 0.f, 0.f, 0.f};
  f32x4 acc[4][4];
#pragma unroll
  for (int a = 0; a < 4; ++a)
#pragma unroll
    for (int c = 0; c < 4; ++c) acc[a][c] = Z4;

  for (int it = 0; it < 8; ++it) {
    int k0 = it << 6;
    __syncthreads();
#pragma unroll
    for (int i = 0; i < 4; ++i) {
      int g   = wv * 4 + i;
      int row = g * 8 + drow;
      ASYNC16(xb + (size_t)(m0 + row) * 512 + k0 + dchk * 8, &As[g * 512]);
    }
#pragma unroll
    for (int i = 0; i < 4; ++i) {
      int g   = wv * 4 + i;
      int row = g * 8 + drow;
      ASYNC16(W + (size_t)(n0 + row) * 512 + k0 + dchk * 8, &Bs[g * 512]);
    }
    __syncthreads();
#pragma unroll
    for (int kk = 0; kk < 2; ++kk) {
      s16x8 af[4], bfr[4];
#pragma unroll
      for (int rb = 0; rb < 4; ++rb) {
        int row = wr + rb * 16 + l16;
        int c   = kk * 4 + quad;
        af[rb] = *(const s16x8*)(As + row * 64 + ((c ^ (row & 7)) * 8));
      }
#pragma unroll
      for (int cb = 0; cb < 4; ++cb) {
        int row = wc + cb * 16 + l16;
        int c   = kk * 4 + quad;
        bfr[cb] = *(const s16x8*)(Bs + row * 64 + ((c ^ (row & 7)) * 8));
      }
#pragma unroll
      for (int rb = 0; rb < 4; ++rb)
#pragma unroll
        for (int cb = 0; cb < 4; ++cb)
          acc[rb][cb] = __builtin_amdgcn_mfma_f32_16x16x32_bf16(af[rb], bfr[cb], acc[rb][cb], 0, 0, 0);
    }
  }

  float bsv[4];
#pragma unroll
  for (int cb = 0; cb < 4; ++cb) bsv[cb] = bias[n0 + wc + cb * 16 + l16];

  if (mat < 2) {
    short* D = (mat == 0) ? Qg : Kg;
#pragma unroll
    for (int rb = 0; rb < 4; ++rb)
#pragma unroll
      for (int cb = 0; cb < 4; ++cb)
#pragma unroll
        for (int r = 0; r < 4; ++r) {
          int m = m0 + wr + rb * 16 + quad * 4 + r;
          D[(size_t)m * 512 + n0 + wc + cb * 16 + l16] =
              (short)f2bf(acc[rb][cb][r] + bsv[cb]);
        }
  } else {
#pragma unroll
    for (int rb = 0; rb < 4; ++rb)
#pragma unroll
      for (int cb = 0; cb < 4; ++cb) {
        u16x4 h;
#pragma unroll
        for (int r = 0; r < 4; ++r) h[r] = f2bf(acc[rb][cb][r] + bsv[cb]);
        int m  = m0 + wr + rb * 16 + quad * 4;
        int bb = m >> 11, s = m & 2047;
        int e  = n0 + wc + cb * 16 + l16;
        *(u16x4*)(VTg + ((size_t)bb * 512 + e) * 2048 + s) = h;
      }
  }
}

// ---------------- kernel 3: flash attention v5 ----------------
// grid = 512 (b = blk&7 -> XCD L2 pinning), 32 Q-rows/block, 4 waves, 2 blocks/CU.
// K tile: 32 keys x 512 E in LDS (32 KB, single buffer, XOR-swizzled).
// V: NEVER in LDS — 8 register fragments loaded from global at iteration top,
//    so they are OLDER than the K-DMA in vmcnt order (consuming them cannot
//    drain the prefetch; barrier(1)'s vmcnt(0) is covered by the QK phase).
// wave w: QK rows a=w&1 (16), keys h=w>>1 (16); PV E-chunk e0=w*128, all 32 rows.
__global__ __launch_bounds__(256, 2) void attn_kernel(
    const short* __restrict__ Qg, const short* __restrict__ Kg,
    const short* __restrict__ VTg, float* __restrict__ out) {
  __shared__ __align__(16) short Kt[32 * 512];   // 32 KB, [key][chunk^(key&7)]
  __shared__ __align__(16) short Pl[32 * 40];    // 2.5 KB, row stride 40 shorts
  __shared__ float l_l[32];
  const float SCL2 = 0.06375871855f;  // log2(e)/sqrt(512)

  int b = blockIdx.x & 7, qt = blockIdx.x >> 3;
  int s0 = qt << 5;
  int tid = threadIdx.x, lane = tid & 63, wv = tid >> 6;
  int l16 = lane & 15, quad = lane >> 4;
  int a = wv & 1, h = wv >> 1;
  int e0 = wv << 7;

  const short* Kb = Kg  + ((size_t)b * S_LEN) * 512;
  const short* Vb = VTg + ((size_t)b * 512) * 2048;

  // K-DMA per-lane base addresses (8 rows per wave, r = wv*8+i, r&7 == i)
  const short* kdma[8];
#pragma unroll
  for (int i = 0; i < 8; ++i)
    kdma[i] = Kb + (size_t)(wv * 8 + i) * 512 + ((lane ^ i) * 8);

  // ---- prologue: stage K tile 0, load Q frags ----
#pragma unroll
  for (int i = 0; i < 8; ++i)
    ASYNC16(kdma[i], &Kt[(wv * 8 + i) * 512]);

  const short* qrow = Qg + ((size_t)b * S_LEN + s0 + a * 16 + l16) * 512 + quad * 8;
  s16x8 qf[16];
#pragma unroll
  for (int kk = 0; kk < 16; ++kk) qf[kk] = *(const s16x8*)(qrow + kk * 32);

  const f32x4 Z4 = {0.f, 0.f, 0.f, 0.f};
  f32x4 acc[2][8];
#pragma unroll
  for (int rb = 0; rb < 2; ++rb)
#pragma unroll
    for (int cb = 0; cb < 8; ++cb) acc[rb][cb] = Z4;
  f32x4 lsum = Z4;                 // rows quad*4+r of group a, keys h*16+l16

  // V fragment lane base: e = e0 + cb*16 + l16, k = kt*32 + quad*8 + j
  const short* vrow = Vb + (size_t)(e0 + l16) * 2048 + quad * 8;

  __syncthreads();                 // K tile 0 ready

  for (int kt = 0; kt < 64; ++kt) {
    // ---- V register fragments for THIS tile, issued before anything else ----
    s16x8 vf[8];
#pragma unroll
    for (int cb = 0; cb < 8; ++cb)
      vf[cb] = *(const s16x8*)(vrow + (size_t)cb * 32768 + kt * 32);

    // ---- QK: S[16 rows(a) x 16 keys(h)] ; two independent MFMA chains ----
    f32x4 s_a = Z4, s_b = Z4;
    int krow = h * 16 + l16;
    const short* kb = &Kt[krow * 512];
    int ksw = krow & 7;
#pragma unroll
    for (int kk = 0; kk < 8; ++kk) {
      s16x8 kf0 = *(const s16x8*)(kb + (((2 * kk) * 4 + quad) ^ ksw) * 8);
      s_a = __builtin_amdgcn_mfma_f32_16x16x32_bf16(qf[2 * kk], kf0, s_a, 0, 0, 0);
      s16x8 kf1 = *(const s16x8*)(kb + (((2 * kk + 1) * 4 + quad) ^ ksw) * 8);
      s_b = __builtin_amdgcn_mfma_f32_16x16x32_bf16(qf[2 * kk + 1], kf1, s_b, 0, 0, 0);
    }
    f32x4 sv = s_a + s_b;

    // ---- no-max softmax: p = exp2(s*SCL2); per-lane row-sum accumulate ----
#pragma unroll
    for (int r = 0; r < 4; ++r) {
      float p = exp2f(sv[r] * SCL2);
      lsum[r] += p;
      Pl[(a * 16 + quad * 4 + r) * 40 + h * 16 + l16] = (short)f2bf(p);
    }

    __syncthreads();   // (1) Kt reads done; P visible; vf drained (covered by QK)

    // ---- issue K-DMA(kt+1): writes Kt; PV reads only Pl + vf registers ----
    if (kt + 1 < 64) {
      size_t adv = (size_t)(kt + 1) * 32 * 512;
#pragma unroll
      for (int i = 0; i < 8; ++i)
        ASYNC16(kdma[i] + adv, &Kt[(wv * 8 + i) * 512]);
    }

    // ---- PV: O[32 x 128chunk] += P[32x32] @ V[32 x 128chunk] (V in regs) ----
    s16x8 pf[2];
#pragma unroll
    for (int rb = 0; rb < 2; ++rb)
      pf[rb] = *(const s16x8*)(Pl + (rb * 16 + l16) * 40 + quad * 8);
#pragma unroll
    for (int cb = 0; cb < 8; ++cb) {
#pragma unroll
      for (int rb = 0; rb < 2; ++rb)
        acc[rb][cb] = __builtin_amdgcn_mfma_f32_16x16x32_bf16(pf[rb], vf[cb], acc[rb][cb], 0, 0, 0);
    }

    __syncthreads();   // (2) PV done (Pl free); K-DMA(kt+1) drained
  }

  // ---- epilogue: combine row sums, divide, store fp32 ----
#pragma unroll
  for (int r = 0; r < 4; ++r) {
    float v = lsum[r];
    v += __shfl_xor(v, 1);
    v += __shfl_xor(v, 2);
    v += __shfl_xor(v, 4);
    v += __shfl_xor(v, 8);
    lsum[r] = v;                    // sum over this wave's 16-key half
  }
  if (h == 0 && l16 == 0) {
#pragma unroll
    for (int r = 0; r < 4; ++r) l_l[a * 16 + quad * 4 + r] = lsum[r];
  }
  __syncthreads();
  if (h == 1 && l16 == 0) {
#pragma unroll
    for (int r = 0; r < 4; ++r) l_l[a * 16 + quad * 4 + r] += lsum[r];
  }
  __syncthreads();

#pragma unroll
  for (int rb = 0; rb < 2; ++rb) {
    f32x4 lv = *(const f32x4*)(l_l + rb * 16 + quad * 4);
    f32x4 li;
#pragma unroll
    for (int r = 0; r < 4; ++r) li[r] = 1.0f / lv[r];
#pragma unroll
    for (int cb = 0; cb < 8; ++cb)
#pragma unroll
      for (int r = 0; r < 4; ++r)
        out[((size_t)b * S_LEN + s0 + rb * 16 + quad * 4 + r) * 512 + e0 + cb * 16 + l16] =
            acc[rb][cb][r] * li[r];
  }
}

// ---------------- host launch ----------------
extern "C" void kernel_launch(void* const* d_in, const int* in_sizes, int n_in,
                              void* d_out, int out_size, void* d_ws, size_t ws_size,
                              hipStream_t stream) {
  const float* x  = (const float*)d_in[0];
  const float* Wq = (const float*)d_in[1];
  const float* bq = (const float*)d_in[2];
  const float* Wk = (const float*)d_in[3];
  const float* bk = (const float*)d_in[4];
  const float* Wv = (const float*)d_in[5];
  const float* bv = (const float*)d_in[6];

  short* Wt  = (short*)d_ws;
  short* xb  = (short*)((char*)d_ws + 1572864);
  short* Qg  = xb + (size_t)8388608;
  short* Kg  = Qg + (size_t)8388608;
  short* VTg = Kg + (size_t)8388608;

  conv_kernel<<<7168, 256, 0, stream>>>(x, Wq, Wk, Wv, xb, Wt);
  qkv_gemm<<<1536, 256, 0, stream>>>(xb, Wt, bq, bk, bv, Qg, Kg, VTg);
  attn_kernel<<<512, 256, 0, stream>>>(Qg, Kg, VTg, (float*)d_out);
}

// Round 7
// 284.138 us; speedup vs baseline: 1.3399x; 1.0209x over previous
//
#include <hip/hip_runtime.h>
#include <stdint.h>

// Self-attention, B=8 S=2048 D=E=512, fp32 in/out, bf16 MFMA internally.
//   conv:     x fp32 -> bf16 AND W[k][n] fp32 -> Wt[n][k] bf16 (merged launch)
//   qkv_gemm: m97-style async-staged GEMM; Q,K row-major bf16; V transposed
//             [B,E,S] bf16 with LDS-transposed, fully-coalesced epilogue store
//   attn:     R3-exact (best verified: 141 us, at its LDS-BW roofline):
//             32 Q-rows/block, 32-key tiles, V+K via global_load_lds, alias-safe
//             single-buffer pipeline, 2 blocks/CU, no-max softmax.

using f32x4 = __attribute__((ext_vector_type(4))) float;
using s16x8 = __attribute__((ext_vector_type(8))) short;
using u16x4 = __attribute__((ext_vector_type(4))) unsigned short;

#define S_LEN 2048
#define EMB   512

#define ASYNC16(g, l)                                                     \
  __builtin_amdgcn_global_load_lds(                                       \
      (const __attribute__((address_space(1))) void*)(g),                 \
      (__attribute__((address_space(3))) void*)(l), 16, 0, 0)

__device__ __forceinline__ unsigned short f2bf(float f) {
  union { float f; unsigned u; } v; v.f = f;
  unsigned r = v.u + 0x7fffu + ((v.u >> 16) & 1u);   // RNE
  return (unsigned short)(r >> 16);
}

// ---------------- kernel 0+1 merged: x conv & weight transpose ----------------
__global__ __launch_bounds__(256) void conv_kernel(
    const float* __restrict__ x, const float* __restrict__ Wq,
    const float* __restrict__ Wk, const float* __restrict__ Wv,
    short* __restrict__ xb, short* __restrict__ Wt) {
  int bid = blockIdx.x;
  if (bid < 4096) {
    int i = (bid * 256 + threadIdx.x) * 8;
    f32x4 a = *(const f32x4*)(x + i);
    f32x4 b = *(const f32x4*)(x + i + 4);
    s16x8 h;
    h[0] = (short)f2bf(a[0]); h[1] = (short)f2bf(a[1]);
    h[2] = (short)f2bf(a[2]); h[3] = (short)f2bf(a[3]);
    h[4] = (short)f2bf(b[0]); h[5] = (short)f2bf(b[1]);
    h[6] = (short)f2bf(b[2]); h[7] = (short)f2bf(b[3]);
    *(s16x8*)(xb + i) = h;
  } else {
    int idx = (bid - 4096) * 256 + threadIdx.x;
    int mat = idx >> 18;
    int r   = idx & 262143;
    int n   = r >> 9;
    int k   = r & 511;
    const float* W = (mat == 0) ? Wq : (mat == 1) ? Wk : Wv;
    Wt[idx] = (short)f2bf(W[k * 512 + n]);
  }
}

// ---------------- kernel 2: QKV projection GEMM (m97 structure) ----------------
// V epilogue: transpose 128x128 tile through LDS (stride 132 -> conflict-free
// writes), then store VT in 256B-coalesced runs instead of 8B/4KB-stride scatter.
__global__ __launch_bounds__(256) void qkv_gemm(
    const short* __restrict__ xb, const short* __restrict__ Wt,
    const float* __restrict__ bq, const float* __restrict__ bk,
    const float* __restrict__ bv,
    short* __restrict__ Qg, short* __restrict__ Kg, short* __restrict__ VTg) {
  __shared__ __align__(16) short smem[128 * 132];   // 33 KB; As/Bs alias front
  short* As = smem;                                  // 128*64
  short* Bs = smem + 8192;                           // 128*64
  int gid = blockIdx.x;
  int mat = gid >> 9;
  int rem = gid & 511;
  int mt  = rem & 127, nt = rem >> 7;
  int m0  = mt << 7,   n0 = nt << 7;
  const short* W    = Wt + (size_t)mat * 262144;
  const float* bias = (mat == 0) ? bq : (mat == 1) ? bk : bv;

  int tid = threadIdx.x, lane = tid & 63, wv = tid >> 6;
  int l16 = lane & 15, quad = lane >> 4;
  int wr = (wv & 1) << 6, wc = (wv >> 1) << 6;
  int drow = lane >> 3;
  int dchk = (lane & 7) ^ drow;

  const f32x4 Z4 = {0.f, 0.f, 0.f, 0.f};
  f32x4 acc[4][4];
#pragma unroll
  for (int a = 0; a < 4; ++a)
#pragma unroll
    for (int c = 0; c < 4; ++c) acc[a][c] = Z4;

  for (int it = 0; it < 8; ++it) {
    int k0 = it << 6;
    __syncthreads();
#pragma unroll
    for (int i = 0; i < 4; ++i) {
      int g   = wv * 4 + i;
      int row = g * 8 + drow;
      ASYNC16(xb + (size_t)(m0 + row) * 512 + k0 + dchk * 8, &As[g * 512]);
    }
#pragma unroll
    for (int i = 0; i < 4; ++i) {
      int g   = wv * 4 + i;
      int row = g * 8 + drow;
      ASYNC16(W + (size_t)(n0 + row) * 512 + k0 + dchk * 8, &Bs[g * 512]);
    }
    __syncthreads();
#pragma unroll
    for (int kk = 0; kk < 2; ++kk) {
      s16x8 af[4], bfr[4];
#pragma unroll
      for (int rb = 0; rb < 4; ++rb) {
        int row = wr + rb * 16 + l16;
        int c   = kk * 4 + quad;
        af[rb] = *(const s16x8*)(As + row * 64 + ((c ^ (row & 7)) * 8));
      }
#pragma unroll
      for (int cb = 0; cb < 4; ++cb) {
        int row = wc + cb * 16 + l16;
        int c   = kk * 4 + quad;
        bfr[cb] = *(const s16x8*)(Bs + row * 64 + ((c ^ (row & 7)) * 8));
      }
#pragma unroll
      for (int rb = 0; rb < 4; ++rb)
#pragma unroll
        for (int cb = 0; cb < 4; ++cb)
          acc[rb][cb] = __builtin_amdgcn_mfma_f32_16x16x32_bf16(af[rb], bfr[cb], acc[rb][cb], 0, 0, 0);
    }
  }

  float bsv[4];
#pragma unroll
  for (int cb = 0; cb < 4; ++cb) bsv[cb] = bias[n0 + wc + cb * 16 + l16];

  if (mat < 2) {
    short* D = (mat == 0) ? Qg : Kg;
#pragma unroll
    for (int rb = 0; rb < 4; ++rb)
#pragma unroll
      for (int cb = 0; cb < 4; ++cb)
#pragma unroll
        for (int r = 0; r < 4; ++r) {
          int m = m0 + wr + rb * 16 + quad * 4 + r;
          D[(size_t)m * 512 + n0 + wc + cb * 16 + l16] =
              (short)f2bf(acc[rb][cb][r] + bsv[cb]);
        }
  } else {
    // ---- V: transpose tile through LDS, store coalesced ----
    __syncthreads();    // all MFMA frag reads of As/Bs done before overwrite
#pragma unroll
    for (int rb = 0; rb < 4; ++rb)
#pragma unroll
      for (int cb = 0; cb < 4; ++cb) {
        int ln = wc + cb * 16 + l16;               // local e
#pragma unroll
        for (int r = 0; r < 4; ++r) {
          int lm = wr + rb * 16 + quad * 4 + r;    // local s
          smem[lm * 132 + ln] = (short)f2bf(acc[rb][cb][r] + bsv[cb]);
        }
      }
    __syncthreads();
    // store: thread t -> 16B chunk c = t&15 (s-range c*8..c*8+7),
    //        e rows (t>>4)*8 .. +7 ; 16 consecutive lanes = 256B run
    int bb = m0 >> 11, sloc = m0 & 2047;
    int c  = tid & 15;
    int eb = (tid >> 4) * 8;
#pragma unroll
    for (int i = 0; i < 8; ++i) {
      int e = eb + i;
      s16x8 h;
#pragma unroll
      for (int j = 0; j < 8; ++j) h[j] = smem[(c * 8 + j) * 132 + e];
      *(s16x8*)(VTg + ((size_t)bb * 512 + n0 + e) * 2048 + sloc + c * 8) = h;
    }
  }
}

// ---------------- kernel 3: flash attention (R3-exact) ----------------
// grid = 512 blocks (b = blk&7 -> XCD L2 pinning), 32 Q-rows/block, 4 waves,
// 68 KB LDS -> 2 blocks/CU (8 waves/CU).
// wave w: row-group a=w&1 (16 rows), key-half h=w>>1 (16 keys) for QK;
//         E-chunk e0=w*128 for PV.  No-max softmax: p = exp2(s*SCL2) directly.
__global__ __launch_bounds__(256, 2) void attn_kernel(
    const short* __restrict__ Qg, const short* __restrict__ Kg,
    const short* __restrict__ VTg, float* __restrict__ out) {
  __shared__ __align__(16) short Kt[32 * 512];   // 32 KB, [key][chunk^(key&7)]
  __shared__ __align__(16) short Vt[512 * 32];   // 32 KB, [e][chunk^((e>>1)&3)]
  __shared__ __align__(16) short Pl[32 * 48];    // 3 KB, row stride 48 shorts
  __shared__ float l_l[32];
  const float SCL2 = 0.06375871855f;  // log2(e)/sqrt(512)

  int b = blockIdx.x & 7, qt = blockIdx.x >> 3;
  int s0 = qt << 5;
  int tid = threadIdx.x, lane = tid & 63, wv = tid >> 6;
  int l16 = lane & 15, quad = lane >> 4;
  int a = wv & 1, h = wv >> 1;
  int e0 = wv << 7;

  const short* Kb = Kg  + ((size_t)b * S_LEN) * 512;
  const short* Vb = VTg + ((size_t)b * 512) * 2048;

  // DMA per-lane base addresses (loop-invariant parts)
  const short* kdma[8];
#pragma unroll
  for (int i = 0; i < 8; ++i) {
    int r = wv * 8 + i;
    kdma[i] = Kb + (size_t)r * 512 + ((lane ^ (i & 7)) * 8);
  }
  int v_er = lane >> 2;
  const short* vdma[8];
#pragma unroll
  for (int i = 0; i < 8; ++i) {
    int g = wv * 8 + i;
    int e = g * 16 + v_er;
    int vc = (lane & 3) ^ ((e >> 1) & 3);
    vdma[i] = Vb + (size_t)e * 2048 + vc * 8;
  }

  // ---- prologue: stage K tile 0, load Q frags ----
#pragma unroll
  for (int i = 0; i < 8; ++i)
    ASYNC16(kdma[i], &Kt[(wv * 8 + i) * 512]);

  const short* qrow = Qg + ((size_t)b * S_LEN + s0 + a * 16 + l16) * 512 + quad * 8;
  s16x8 qf[16];
#pragma unroll
  for (int kk = 0; kk < 16; ++kk) qf[kk] = *(const s16x8*)(qrow + kk * 32);

  const f32x4 Z4 = {0.f, 0.f, 0.f, 0.f};
  f32x4 acc[2][8];
#pragma unroll
  for (int rb = 0; rb < 2; ++rb)
#pragma unroll
    for (int cb = 0; cb < 8; ++cb) acc[rb][cb] = Z4;
  f32x4 lsum = Z4;                 // rows quad*4+r of group a, keys h*16+l16

  __syncthreads();                 // K tile 0 ready

  for (int kt = 0; kt < 64; ++kt) {
    int t0 = kt << 5;
    // ---- issue V-DMA(kt): writes Vt; this phase reads only Kt/Pl -> alias-safe ----
#pragma unroll
    for (int i = 0; i < 8; ++i)
      ASYNC16(vdma[i] + t0, &Vt[(wv * 8 + i) * 512]);

    // ---- QK: S[16 rows(a) x 16 keys(h)] ; two independent MFMA chains ----
    f32x4 s_a = Z4, s_b = Z4;
    int krow = h * 16 + l16;
    const short* kb = &Kt[krow * 512];
    int ksw = (krow & 7);
#pragma unroll
    for (int kk = 0; kk < 8; ++kk) {
      s16x8 kf0 = *(const s16x8*)(kb + (((2 * kk) * 4 + quad) ^ ksw) * 8);
      s_a = __builtin_amdgcn_mfma_f32_16x16x32_bf16(qf[2 * kk], kf0, s_a, 0, 0, 0);
      s16x8 kf1 = *(const s16x8*)(kb + (((2 * kk + 1) * 4 + quad) ^ ksw) * 8);
      s_b = __builtin_amdgcn_mfma_f32_16x16x32_bf16(qf[2 * kk + 1], kf1, s_b, 0, 0, 0);
    }
    f32x4 sv = s_a + s_b;

    // ---- no-max softmax: p = exp2(s * SCL2); per-lane row-sum accumulate ----
#pragma unroll
    for (int r = 0; r < 4; ++r) {
      float p = exp2f(sv[r] * SCL2);
      lsum[r] += p;
      Pl[(a * 16 + quad * 4 + r) * 48 + h * 16 + l16] = (short)f2bf(p);
    }

    __syncthreads();   // (1) Kt reads done; P visible; V-DMA(kt) drained

    // ---- issue K-DMA(kt+1): writes Kt; PV reads only Pl/Vt -> alias-safe ----
    if (kt + 1 < 64) {
      size_t adv = (size_t)(kt + 1) * 32 * 512;
#pragma unroll
      for (int i = 0; i < 8; ++i)
        ASYNC16(kdma[i] + adv, &Kt[(wv * 8 + i) * 512]);
    }

    // ---- PV: O[32 x 128chunk] += P[32x32] @ V[32 x 128chunk] ----
    s16x8 pf[2];
#pragma unroll
    for (int rb = 0; rb < 2; ++rb)
      pf[rb] = *(const s16x8*)(Pl + (rb * 16 + l16) * 48 + quad * 8);
#pragma unroll
    for (int cb = 0; cb < 8; ++cb) {
      int e  = e0 + cb * 16 + l16;
      int pc = quad ^ ((e >> 1) & 3);
      s16x8 vf = *(const s16x8*)(Vt + e * 32 + pc * 8);
#pragma unroll
      for (int rb = 0; rb < 2; ++rb)
        acc[rb][cb] = __builtin_amdgcn_mfma_f32_16x16x32_bf16(pf[rb], vf, acc[rb][cb], 0, 0, 0);
    }

    __syncthreads();   // (2) PV done (Pl/Vt free); K-DMA(kt+1) drained
  }

  // ---- epilogue: combine row sums, divide, store fp32 ----
#pragma unroll
  for (int r = 0; r < 4; ++r) {
    float v = lsum[r];
    v += __shfl_xor(v, 1);
    v += __shfl_xor(v, 2);
    v += __shfl_xor(v, 4);
    v += __shfl_xor(v, 8);
    lsum[r] = v;                    // sum over this wave's 16-key half
  }
  if (h == 0 && l16 == 0) {
#pragma unroll
    for (int r = 0; r < 4; ++r) l_l[a * 16 + quad * 4 + r] = lsum[r];
  }
  __syncthreads();
  if (h == 1 && l16 == 0) {
#pragma unroll
    for (int r = 0; r < 4; ++r) l_l[a * 16 + quad * 4 + r] += lsum[r];
  }
  __syncthreads();

#pragma unroll
  for (int rb = 0; rb < 2; ++rb) {
    f32x4 lv = *(const f32x4*)(l_l + rb * 16 + quad * 4);
    f32x4 li;
#pragma unroll
    for (int r = 0; r < 4; ++r) li[r] = 1.0f / lv[r];
#pragma unroll
    for (int cb = 0; cb < 8; ++cb)
#pragma unroll
      for (int r = 0; r < 4; ++r)
        out[((size_t)b * S_LEN + s0 + rb * 16 + quad * 4 + r) * 512 + e0 + cb * 16 + l16] =
            acc[rb][cb][r] * li[r];
  }
}

// ---------------- host launch ----------------
extern "C" void kernel_launch(void* const* d_in, const int* in_sizes, int n_in,
                              void* d_out, int out_size, void* d_ws, size_t ws_size,
                              hipStream_t stream) {
  const float* x  = (const float*)d_in[0];
  const float* Wq = (const float*)d_in[1];
  const float* bq = (const float*)d_in[2];
  const float* Wk = (const float*)d_in[3];
  const float* bk = (const float*)d_in[4];
  const float* Wv = (const float*)d_in[5];
  const float* bv = (const float*)d_in[6];

  short* Wt  = (short*)d_ws;
  short* xb  = (short*)((char*)d_ws + 1572864);
  short* Qg  = xb + (size_t)8388608;
  short* Kg  = Qg + (size_t)8388608;
  short* VTg = Kg + (size_t)8388608;

  conv_kernel<<<7168, 256, 0, stream>>>(x, Wq, Wk, Wv, xb, Wt);
  qkv_gemm<<<1536, 256, 0, stream>>>(xb, Wt, bq, bk, bv, Qg, Kg, VTg);
  attn_kernel<<<512, 256, 0, stream>>>(Qg, Kg, VTg, (float*)d_out);
}